// Round 1
// baseline (520.364 us; speedup 1.0000x reference)
//
#include <hip/hip_runtime.h>
#include <hip/hip_bf16.h>

#define D_MODEL 512
#define NHEADS 8
#define DK 64
#define WIN 64
#define SEQ 2048
#define BATCH 4
#define ROWS (BATCH*SEQ)

using bf16x8 = __attribute__((ext_vector_type(8))) short;
using f32x4  = __attribute__((ext_vector_type(4))) float;
using u16x4  = __attribute__((ext_vector_type(4))) unsigned short;

__device__ __forceinline__ unsigned short f2b(float f) {
  union { float f; unsigned u; } v; v.f = f;
  unsigned r = v.u + 0x7FFFu + ((v.u >> 16) & 1u);
  return (unsigned short)(r >> 16);
}
__device__ __forceinline__ float b2f(unsigned short h) {
  union { unsigned u; float f; } v; v.u = ((unsigned)h) << 16; return v.f;
}

// ---------------- GEMM: C = A[M,K] @ W[K,N] + bias, fused epilogue ----------
#define EP_QKV  0   // scatter to [B,H,L,dk]
#define EP_RES  1   // + resid -> out
#define EP_RELU 2   // relu -> out

#define BSTR 40  // LDS row stride in shorts (80B = 5*16B; 8 distinct bank spans)

template<int EP>
__global__ __launch_bounds__(256)
void gemm_kernel(const float* __restrict__ A, const float* __restrict__ W,
                 const float* __restrict__ bias, const float* __restrict__ resid,
                 float* __restrict__ out, int K, int N)
{
  __shared__ __align__(16) unsigned short Asl[128*BSTR];
  __shared__ __align__(16) unsigned short Bsl[128*BSTR];

  const int tid = threadIdx.x;
  const int lane = tid & 63, wave = tid >> 6;
  const int wr = wave >> 1, wc = wave & 1;
  const int l15 = lane & 15, lq = lane >> 4;
  const int m0 = blockIdx.y * 128, n0 = blockIdx.x * 128;

  f32x4 acc[4][4] = {};

  for (int k0 = 0; k0 < K; k0 += 32) {
    __syncthreads();
    // stage A tile 128x32 (row-major [m][k], bf16)
    #pragma unroll
    for (int i = 0; i < 4; ++i) {
      int e = tid + i*256;
      int r = e >> 3, kc = (e & 7) << 2;
      float4 v = *reinterpret_cast<const float4*>(A + (size_t)(m0+r)*K + k0 + kc);
      u16x4 hv; hv[0]=f2b(v.x); hv[1]=f2b(v.y); hv[2]=f2b(v.z); hv[3]=f2b(v.w);
      *reinterpret_cast<u16x4*>(&Asl[r*BSTR + kc]) = hv;
    }
    // stage B tile 32x128 transposed -> Bsl[n][k]
    #pragma unroll
    for (int i = 0; i < 16; ++i) {
      int e = tid + i*256;
      int kk = e >> 7, n = e & 127;
      Bsl[n*BSTR + kk] = f2b(W[(size_t)(k0+kk)*N + n0 + n]);
    }
    __syncthreads();
    bf16x8 af[4], bfr[4];
    #pragma unroll
    for (int m = 0; m < 4; ++m)
      af[m] = *reinterpret_cast<const bf16x8*>(&Asl[(wr*64 + m*16 + l15)*BSTR + lq*8]);
    #pragma unroll
    for (int n = 0; n < 4; ++n)
      bfr[n] = *reinterpret_cast<const bf16x8*>(&Bsl[(wc*64 + n*16 + l15)*BSTR + lq*8]);
    #pragma unroll
    for (int m = 0; m < 4; ++m)
      #pragma unroll
      for (int n = 0; n < 4; ++n)
        acc[m][n] = __builtin_amdgcn_mfma_f32_16x16x32_bf16(af[m], bfr[n], acc[m][n], 0, 0, 0);
  }

  // epilogue: C/D layout col=lane&15, row=(lane>>4)*4+j  [m91-verified]
  #pragma unroll
  for (int n = 0; n < 4; ++n) {
    const int col = n0 + wc*64 + n*16 + l15;
    const float bv = bias[col];
    #pragma unroll
    for (int m = 0; m < 4; ++m) {
      #pragma unroll
      for (int j = 0; j < 4; ++j) {
        const int row = m0 + wr*64 + m*16 + lq*4 + j;
        float val = acc[m][n][j] + bv;
        if (EP == EP_QKV) {
          int b = row >> 11, l = row & (SEQ-1);
          int h = col >> 6, d = col & 63;
          out[(((size_t)(b*NHEADS + h))*SEQ + l)*DK + d] = val;
        } else if (EP == EP_RES) {
          size_t o = (size_t)row*N + col;
          out[o] = val + resid[o];
        } else { // EP_RELU
          out[(size_t)row*N + col] = fmaxf(val, 0.0f);
        }
      }
    }
  }
}

// ---------------- sliding-window attention ----------------
// one block (4 waves) per (b, h, 64-query tile); band |i-j| <= WIN
__global__ __launch_bounds__(256)
void attn_kernel(const float* __restrict__ q, const float* __restrict__ k,
                 const float* __restrict__ v, float* __restrict__ ctx)
{
  __shared__ __align__(16) unsigned short Ksl[192*64];
  __shared__ __align__(16) unsigned short Vsl[192*64];
  __shared__ __align__(16) unsigned short Qsl[64*64];
  __shared__ float Psl[4][192];

  const int bid = blockIdx.x;
  const int t = bid & 31, h = (bid >> 5) & 7, b = bid >> 8;
  const int qs = t*64;
  const int ks0 = max(0, qs - WIN);
  const int ks1 = min(SEQ, qs + 64 + WIN);
  const int span = ks1 - ks0;   // 128..192

  const size_t hoff = ((size_t)(b*NHEADS + h))*SEQ*DK;
  const float* kh = k + hoff;
  const float* vh = v + hoff;
  const float* qh = q + hoff;

  const int tid = threadIdx.x;
  // stage K,V (192 rows x 64 d) as bf16, XOR-swizzled rows; zero-fill >= span
  #pragma unroll
  for (int i = 0; i < 12; ++i) {
    int e = tid + i*256;
    int r = e >> 4, c4 = (e & 15) << 2;
    int off = r*64 + ((((c4 << 1) ^ ((r & 7) << 4))) >> 1);
    u16x4 hk{}, hv{};
    if (r < span) {
      float4 kv = *reinterpret_cast<const float4*>(kh + (size_t)(ks0+r)*DK + c4);
      float4 vv = *reinterpret_cast<const float4*>(vh + (size_t)(ks0+r)*DK + c4);
      hk[0]=f2b(kv.x); hk[1]=f2b(kv.y); hk[2]=f2b(kv.z); hk[3]=f2b(kv.w);
      hv[0]=f2b(vv.x); hv[1]=f2b(vv.y); hv[2]=f2b(vv.z); hv[3]=f2b(vv.w);
    }
    *reinterpret_cast<u16x4*>(&Ksl[off]) = hk;
    *reinterpret_cast<u16x4*>(&Vsl[off]) = hv;
  }
  #pragma unroll
  for (int i = 0; i < 4; ++i) {
    int e = tid + i*256;
    int r = e >> 4, c4 = (e & 15) << 2;
    float4 qv = *reinterpret_cast<const float4*>(qh + (size_t)(qs+r)*DK + c4);
    int off = r*64 + ((((c4 << 1) ^ ((r & 7) << 4))) >> 1);
    u16x4 hq; hq[0]=f2b(qv.x); hq[1]=f2b(qv.y); hq[2]=f2b(qv.z); hq[3]=f2b(qv.w);
    *reinterpret_cast<u16x4*>(&Qsl[off]) = hq;
  }
  __syncthreads();

  const int wave = tid >> 6, lane = tid & 63;
  for (int qq = 0; qq < 16; ++qq) {
    const int iq = wave*16 + qq;   // local query 0..63
    const int ig = qs + iq;        // global query
    // broadcast-load q row into registers (f32)
    float qreg[64];
    #pragma unroll
    for (int d2 = 0; d2 < 8; ++d2) {
      bf16x8 qb = *reinterpret_cast<const bf16x8*>(&Qsl[iq*64 + (((d2<<4) ^ ((iq&7)<<4)) >> 1)]);
      #pragma unroll
      for (int u = 0; u < 8; ++u) qreg[d2*8+u] = b2f((unsigned short)qb[u]);
    }
    // scores: lane handles keys lane, lane+64, lane+128
    float s[3];
    #pragma unroll
    for (int c = 0; c < 3; ++c) {
      const int j = c*64 + lane;
      const int jg = ks0 + j;
      bool ok = (j < span) && (jg >= ig - WIN) && (jg <= ig + WIN);
      float dot = 0.0f;
      if (ok) {
        #pragma unroll
        for (int d2 = 0; d2 < 8; ++d2) {
          bf16x8 kb = *reinterpret_cast<const bf16x8*>(&Ksl[j*64 + (((d2<<4) ^ ((j&7)<<4)) >> 1)]);
          #pragma unroll
          for (int u = 0; u < 8; ++u) dot += qreg[d2*8+u]*b2f((unsigned short)kb[u]);
        }
      }
      s[c] = ok ? dot*0.125f : -3.0e38f;
    }
    // wave softmax over 3x64 slots
    float mx = fmaxf(fmaxf(s[0], s[1]), s[2]);
    #pragma unroll
    for (int off = 32; off; off >>= 1) mx = fmaxf(mx, __shfl_xor(mx, off));
    float p0 = __expf(s[0]-mx), p1 = __expf(s[1]-mx), p2 = __expf(s[2]-mx);
    float ps = p0+p1+p2;
    #pragma unroll
    for (int off = 32; off; off >>= 1) ps += __shfl_xor(ps, off);
    const float inv = 1.0f/ps;
    Psl[wave][lane]      = p0*inv;
    Psl[wave][lane+64]   = p1*inv;
    Psl[wave][lane+128]  = p2*inv;
    // PV: lane = output dim d
    const int d = lane;
    const int dblk = (d >> 3) << 4;
    const int dlo = d & 7;
    float acc = 0.0f;
    #pragma unroll 8
    for (int j = 0; j < 192; ++j) {
      float pj = Psl[wave][j];
      acc += pj * b2f(Vsl[j*64 + (((dblk ^ ((j&7)<<4)) >> 1) + dlo)]);
    }
    ctx[((size_t)b*SEQ + ig)*D_MODEL + h*DK + d] = acc;
  }
}

// ---------------- LayerNorm (one wave per row, in-place safe) --------------
__global__ __launch_bounds__(256)
void ln_kernel(const float* __restrict__ in, const float* __restrict__ g,
               const float* __restrict__ bb, float* __restrict__ out)
{
  const int row = blockIdx.x*4 + (threadIdx.x >> 6);
  const int lane = threadIdx.x & 63;
  const float* p = in + (size_t)row*D_MODEL + lane*8;
  float4 v0 = *reinterpret_cast<const float4*>(p);
  float4 v1 = *reinterpret_cast<const float4*>(p + 4);
  float s  = v0.x+v0.y+v0.z+v0.w + v1.x+v1.y+v1.z+v1.w;
  float sq = v0.x*v0.x+v0.y*v0.y+v0.z*v0.z+v0.w*v0.w
           + v1.x*v1.x+v1.y*v1.y+v1.z*v1.z+v1.w*v1.w;
  #pragma unroll
  for (int off = 32; off; off >>= 1) { s += __shfl_xor(s, off); sq += __shfl_xor(sq, off); }
  const float mean = s * (1.0f/D_MODEL);
  const float var  = sq * (1.0f/D_MODEL) - mean*mean;
  const float rstd = rsqrtf(var + 1e-5f);
  float4 g0 = *reinterpret_cast<const float4*>(g + lane*8);
  float4 g1 = *reinterpret_cast<const float4*>(g + lane*8 + 4);
  float4 b0 = *reinterpret_cast<const float4*>(bb + lane*8);
  float4 b1 = *reinterpret_cast<const float4*>(bb + lane*8 + 4);
  float4 o0, o1;
  o0.x = (v0.x-mean)*rstd*g0.x + b0.x;
  o0.y = (v0.y-mean)*rstd*g0.y + b0.y;
  o0.z = (v0.z-mean)*rstd*g0.z + b0.z;
  o0.w = (v0.w-mean)*rstd*g0.w + b0.w;
  o1.x = (v1.x-mean)*rstd*g1.x + b1.x;
  o1.y = (v1.y-mean)*rstd*g1.y + b1.y;
  o1.z = (v1.z-mean)*rstd*g1.z + b1.z;
  o1.w = (v1.w-mean)*rstd*g1.w + b1.w;
  float* qo = out + (size_t)row*D_MODEL + lane*8;
  *reinterpret_cast<float4*>(qo)     = o0;
  *reinterpret_cast<float4*>(qo + 4) = o1;
}

extern "C" void kernel_launch(void* const* d_in, const int* in_sizes, int n_in,
                              void* d_out, int out_size, void* d_ws, size_t ws_size,
                              hipStream_t stream)
{
  (void)in_sizes; (void)n_in; (void)out_size; (void)ws_size;
  const float* x  = (const float*)d_in[0];
  const float* wq = (const float*)d_in[1];
  const float* bq = (const float*)d_in[2];
  const float* wk = (const float*)d_in[3];
  const float* bk = (const float*)d_in[4];
  const float* wv = (const float*)d_in[5];
  const float* bv = (const float*)d_in[6];
  const float* wo = (const float*)d_in[7];
  const float* bo = (const float*)d_in[8];
  const float* g1 = (const float*)d_in[9];
  const float* be1= (const float*)d_in[10];
  const float* w1 = (const float*)d_in[11];
  const float* b1 = (const float*)d_in[12];
  const float* w2 = (const float*)d_in[13];
  const float* b2 = (const float*)d_in[14];
  const float* g2 = (const float*)d_in[15];
  const float* be2= (const float*)d_in[16];

  float* ws = (float*)d_ws;
  const size_t RD = (size_t)ROWS * D_MODEL;
  float* qb   = ws;            // [B,H,L,dk]
  float* kb   = ws + RD;
  float* vb   = ws + 2*RD;
  float* ctx  = ws + 3*RD;     // [B,L,D]
  float* ff1  = ws;            // reuse q/k/v/ctx region: 8192x2048 = 4*RD floats
  float* hbuf = ws + 4*RD;     // post-LN1
  float* pre  = (float*)d_out; // pre-LN buffer lives in d_out (in-place LN)
  float* outp = (float*)d_out;

  dim3 blk(256);
  gemm_kernel<EP_QKV><<<dim3(4,64), blk, 0, stream>>>(x, wq, bq, nullptr, qb, 512, 512);
  gemm_kernel<EP_QKV><<<dim3(4,64), blk, 0, stream>>>(x, wk, bk, nullptr, kb, 512, 512);
  gemm_kernel<EP_QKV><<<dim3(4,64), blk, 0, stream>>>(x, wv, bv, nullptr, vb, 512, 512);
  attn_kernel<<<dim3(BATCH*NHEADS*32), blk, 0, stream>>>(qb, kb, vb, ctx);
  gemm_kernel<EP_RES><<<dim3(4,64), blk, 0, stream>>>(ctx, wo, bo, x, pre, 512, 512);
  ln_kernel<<<dim3(ROWS/4), blk, 0, stream>>>(pre, g1, be1, hbuf);
  gemm_kernel<EP_RELU><<<dim3(16,64), blk, 0, stream>>>(hbuf, w1, b1, nullptr, ff1, 512, 2048);
  gemm_kernel<EP_RES><<<dim3(4,64), blk, 0, stream>>>(ff1, w2, b2, hbuf, pre, 2048, 512);
  ln_kernel<<<dim3(ROWS/4), blk, 0, stream>>>(pre, g2, be2, outp);
}

// Round 3
// 353.477 us; speedup vs baseline: 1.4721x; 1.4721x over previous
//
#include <hip/hip_runtime.h>
#include <hip/hip_bf16.h>

#define D_MODEL 512
#define NHEADS 8
#define DK 64
#define WIN 64
#define SEQ 2048
#define BATCH 4
#define ROWS (BATCH*SEQ)

typedef unsigned short u16;
using bf16x8 = __attribute__((ext_vector_type(8))) short;
using f32x4  = __attribute__((ext_vector_type(4))) float;
using u16x4  = __attribute__((ext_vector_type(4))) unsigned short;

__device__ __forceinline__ u16 f2b(float f) {
  union { float f; unsigned u; } v; v.f = f;
  unsigned r = v.u + 0x7FFFu + ((v.u >> 16) & 1u);
  return (u16)(r >> 16);
}
__device__ __forceinline__ float b2f(u16 h) {
  union { unsigned u; float f; } v; v.u = ((unsigned)h) << 16; return v.f;
}

// ================= GEMM main loop (128x128 tile, BK=32) ====================
// Asl: [128][40] rows of A (bf16). Bsl: [128][40] rows of W^T (bf16),
// k-chunks XOR-swizzled by ((n>>2)&3) to cut transpose-write conflicts.
template<bool ABF16>
__device__ __forceinline__ void gemm_mainloop(
    const void* A_, const float* W, int K, int N, int m0, int n0, int tid,
    f32x4 (&acc)[4][4], u16* Asl, u16* Bsl)
{
  const int lane = tid & 63, wave = tid >> 6;
  const int wr = wave >> 1, wc = wave & 1;
  const int l15 = lane & 15, lq = lane >> 4;

  for (int k0 = 0; k0 < K; k0 += 32) {
    __syncthreads();
    if (ABF16) {
      const u16* A = (const u16*)A_;
      #pragma unroll
      for (int i = 0; i < 2; ++i) {
        int e = tid + i*256;
        int r = e >> 2, kc = (e & 3) << 3;
        *(bf16x8*)(&Asl[r*40 + kc]) =
            *(const bf16x8*)(A + (size_t)(m0+r)*K + k0 + kc);
      }
    } else {
      const float* A = (const float*)A_;
      #pragma unroll
      for (int i = 0; i < 4; ++i) {
        int e = tid + i*256;
        int r = e >> 3, kc = (e & 7) << 2;
        float4 v = *(const float4*)(A + (size_t)(m0+r)*K + k0 + kc);
        u16x4 hv; hv[0]=f2b(v.x); hv[1]=f2b(v.y); hv[2]=f2b(v.z); hv[3]=f2b(v.w);
        *(u16x4*)(&Asl[r*40 + kc]) = hv;
      }
    }
    #pragma unroll
    for (int i = 0; i < 4; ++i) {
      int e = tid + i*256;
      int kk = e >> 5, n4 = (e & 31) << 2;
      float4 w4 = *(const float4*)(W + (size_t)(k0+kk)*N + n0 + n4);
      float vv[4] = {w4.x, w4.y, w4.z, w4.w};
      #pragma unroll
      for (int u = 0; u < 4; ++u) {
        int n = n4 + u;
        int col = ((((kk>>3) ^ ((n>>2)&3)) << 3) | (kk & 7));
        Bsl[n*40 + col] = f2b(vv[u]);
      }
    }
    __syncthreads();
    bf16x8 af[4], bfr[4];
    #pragma unroll
    for (int m = 0; m < 4; ++m)
      af[m] = *(const bf16x8*)(&Asl[(wr*64 + m*16 + l15)*40 + lq*8]);
    #pragma unroll
    for (int n = 0; n < 4; ++n) {
      int nr = wc*64 + n*16 + l15;
      bfr[n] = *(const bf16x8*)(&Bsl[nr*40 + ((lq ^ ((nr>>2)&3)) << 3)]);
    }
    #pragma unroll
    for (int m = 0; m < 4; ++m)
      #pragma unroll
      for (int n = 0; n < 4; ++n)
        acc[m][n] = __builtin_amdgcn_mfma_f32_16x16x32_bf16(af[m], bfr[n], acc[m][n], 0, 0, 0);
  }
}

// ---------------- fused QKV: grid.z selects (W, bias, out) -----------------
__global__ __launch_bounds__(256)
void qkv_kernel(const float* __restrict__ x,
                const float* __restrict__ wq, const float* __restrict__ bq,
                const float* __restrict__ wk, const float* __restrict__ bk,
                const float* __restrict__ wv, const float* __restrict__ bv,
                u16* __restrict__ qo, u16* __restrict__ ko, u16* __restrict__ vo)
{
  __shared__ __align__(16) u16 Asl[128*40];
  __shared__ __align__(16) u16 Bsl[128*40];
  const float* W; const float* bias; u16* out;
  if (blockIdx.z == 0)      { W = wq; bias = bq; out = qo; }
  else if (blockIdx.z == 1) { W = wk; bias = bk; out = ko; }
  else                      { W = wv; bias = bv; out = vo; }

  const int tid = threadIdx.x;
  const int lane = tid & 63, wave = tid >> 6;
  const int wr = wave >> 1, wc = wave & 1;
  const int l15 = lane & 15, lq = lane >> 4;
  const int m0 = blockIdx.y * 128, n0 = blockIdx.x * 128;

  f32x4 acc[4][4] = {};
  gemm_mainloop<false>(x, W, 512, 512, m0, n0, tid, acc, Asl, Bsl);

  #pragma unroll
  for (int n = 0; n < 4; ++n) {
    const int col = n0 + wc*64 + n*16 + l15;
    const float bv2 = bias[col];
    const int h = col >> 6, d = col & 63;
    #pragma unroll
    for (int m = 0; m < 4; ++m)
      #pragma unroll
      for (int j = 0; j < 4; ++j) {
        const int row = m0 + wr*64 + m*16 + lq*4 + j;
        const int b = row >> 11, l = row & (SEQ-1);
        out[(((size_t)(b*NHEADS + h))*SEQ + l)*DK + d] = f2b(acc[m][n][j] + bv2);
      }
  }
}

// ---------------- generic GEMM with epilogue -------------------------------
#define EP_RES  1   // f32 out = acc + bias + resid
#define EP_RELU 2   // bf16 out = relu(acc + bias)

template<int EP, bool ABF16>
__global__ __launch_bounds__(256)
void gemm_kernel(const void* __restrict__ A_, const float* __restrict__ W,
                 const float* __restrict__ bias, const float* __restrict__ resid,
                 void* __restrict__ out_, int K, int N)
{
  __shared__ __align__(16) u16 Asl[128*40];
  __shared__ __align__(16) u16 Bsl[128*40];

  const int tid = threadIdx.x;
  const int lane = tid & 63, wave = tid >> 6;
  const int wr = wave >> 1, wc = wave & 1;
  const int l15 = lane & 15, lq = lane >> 4;
  const int m0 = blockIdx.y * 128, n0 = blockIdx.x * 128;

  f32x4 acc[4][4] = {};
  gemm_mainloop<ABF16>(A_, W, K, N, m0, n0, tid, acc, Asl, Bsl);

  #pragma unroll
  for (int n = 0; n < 4; ++n) {
    const int col = n0 + wc*64 + n*16 + l15;
    const float bv2 = bias[col];
    #pragma unroll
    for (int m = 0; m < 4; ++m)
      #pragma unroll
      for (int j = 0; j < 4; ++j) {
        const int row = m0 + wr*64 + m*16 + lq*4 + j;
        const size_t o = (size_t)row*N + col;
        float val = acc[m][n][j] + bv2;
        if (EP == EP_RES)  ((float*)out_)[o] = val + resid[o];
        else               ((u16*)out_)[o]   = f2b(fmaxf(val, 0.0f));
      }
  }
}

// ================= MFMA sliding-window attention ===========================
// one block (4 waves) per (b, h, 64-query tile).  Each wave owns 16 queries.
// S^T = K·Q^T (swapped operands -> softmax is a 4-lane reduce), P via LDS,
// O = P·(V^T rows).
__global__ __launch_bounds__(256)
void attn_kernel(const u16* __restrict__ q, const u16* __restrict__ k,
                 const u16* __restrict__ v, float* __restrict__ ctx)
{
  __shared__ __align__(16) u16 Ksl[192*40];     // K rows [j][40]
  __shared__ __align__(16) u16 Vt[64*200];      // V^T rows [d][200], swizzled
  __shared__ __align__(16) u16 Pl[4][16*200];   // per-wave P rows [i][200]

  const int bid = blockIdx.x;
  const int t = bid & 31, h = (bid >> 5) & 7, b = bid >> 8;
  const int qs = t*64;
  const int ks0 = max(0, qs - WIN);
  const int ks1 = min(SEQ, qs + 64 + WIN);
  const int span = ks1 - ks0;                   // 128..192

  const size_t hoff = ((size_t)(b*NHEADS + h))*SEQ*DK;
  const u16* kh = k + hoff;
  const u16* vh = v + hoff;
  const int tid = threadIdx.x;

  // stage K rows (zero-fill beyond span)
  #pragma unroll
  for (int i = 0; i < 6; ++i) {
    int e = tid + i*256;                        // 1536 units of 8 shorts
    int r = e >> 3, c8 = (e & 7) << 3;
    bf16x8 val = {};
    if (r < span) val = *(const bf16x8*)(kh + (size_t)(ks0+r)*DK + c8);
    *(bf16x8*)(&Ksl[r*40 + c8]) = val;
  }
  // stage V transposed: Vt[d][col], col = ((j>>3)^((d>>2)&7))*8 | (j&7)
  #pragma unroll
  for (int i = 0; i < 12; ++i) {
    int e = tid + i*256;                        // 3072 units of 4 shorts
    int j = e >> 4, d4 = (e & 15) << 2;
    u16x4 val{};
    if (j < span) val = *(const u16x4*)(vh + (size_t)(ks0+j)*DK + d4);
    #pragma unroll
    for (int u = 0; u < 4; ++u) {
      int d = d4 + u;
      int col = ((((j >> 3) ^ ((d >> 2) & 7)) << 3) | (j & 7));
      Vt[d*200 + col] = (u16)val[u];
    }
  }
  __syncthreads();

  const int wave = tid >> 6, lane = tid & 63;
  const int lq = lane >> 4, l15 = lane & 15;

  // Q B-fragments straight from global (bf16)
  const u16* qrow = q + hoff + (size_t)(qs + wave*16 + l15)*DK;
  const bf16x8 qf0 = *(const bf16x8*)(qrow + lq*8);
  const bf16x8 qf1 = *(const bf16x8*)(qrow + 32 + lq*8);

  // S^T: rows j (12 fragments of 16), cols i (this wave's 16 queries)
  f32x4 sacc[12];
  #pragma unroll
  for (int m = 0; m < 12; ++m) sacc[m] = f32x4{0.f,0.f,0.f,0.f};
  #pragma unroll
  for (int m = 0; m < 12; ++m) {
    const u16* kr = &Ksl[(m*16 + l15)*40];
    bf16x8 ka0 = *(const bf16x8*)(kr + lq*8);
    bf16x8 ka1 = *(const bf16x8*)(kr + 32 + lq*8);
    sacc[m] = __builtin_amdgcn_mfma_f32_16x16x32_bf16(ka0, qf0, sacc[m], 0, 0, 0);
    sacc[m] = __builtin_amdgcn_mfma_f32_16x16x32_bf16(ka1, qf1, sacc[m], 0, 0, 0);
  }

  // mask + softmax (reduce over 4 lanes sharing l15: xor 16, 32)
  const int ig = qs + wave*16 + l15;            // this lane's query index
  float mx = -3.0e38f;
  #pragma unroll
  for (int m = 0; m < 12; ++m)
    #pragma unroll
    for (int r = 0; r < 4; ++r) {
      int jg = ks0 + m*16 + lq*4 + r;
      bool ok = (jg < ks1) && (jg >= ig - WIN) && (jg <= ig + WIN);
      float sv = ok ? sacc[m][r]*0.125f : -3.0e38f;
      sacc[m][r] = sv;
      mx = fmaxf(mx, sv);
    }
  mx = fmaxf(mx, __shfl_xor(mx, 16));
  mx = fmaxf(mx, __shfl_xor(mx, 32));
  float sum = 0.f;
  #pragma unroll
  for (int m = 0; m < 12; ++m)
    #pragma unroll
    for (int r = 0; r < 4; ++r) {
      float p = __expf(sacc[m][r] - mx);
      sacc[m][r] = p;
      sum += p;
    }
  sum += __shfl_xor(sum, 16);
  sum += __shfl_xor(sum, 32);
  const float inv = 1.0f / sum;

  // write normalized P (bf16) to this wave's LDS region: row i=l15, j packed
  u16* pw = &Pl[wave][0];
  #pragma unroll
  for (int m = 0; m < 12; ++m) {
    unsigned lo = (unsigned)f2b(sacc[m][0]*inv) | ((unsigned)f2b(sacc[m][1]*inv) << 16);
    unsigned hi = (unsigned)f2b(sacc[m][2]*inv) | ((unsigned)f2b(sacc[m][3]*inv) << 16);
    uint2 pk = make_uint2(lo, hi);
    *(uint2*)(&pw[l15*200 + m*16 + lq*4]) = pk;
  }

  // PV: O[16][64] = P[16][192] · Vt-rows[64][192]
  f32x4 oacc[4] = {};
  #pragma unroll
  for (int kst = 0; kst < 6; ++kst) {
    bf16x8 pa = *(const bf16x8*)(&pw[l15*200 + kst*32 + lq*8]);
    #pragma unroll
    for (int n = 0; n < 4; ++n) {
      int d = n*16 + l15;
      int col = (((kst*4 + lq) ^ ((d >> 2) & 7)) << 3);
      bf16x8 vb = *(const bf16x8*)(&Vt[d*200 + col]);
      oacc[n] = __builtin_amdgcn_mfma_f32_16x16x32_bf16(pa, vb, oacc[n], 0, 0, 0);
    }
  }

  // C[i][d]: row = lq*4+r (query), col = l15 (d within n-block)
  #pragma unroll
  for (int n = 0; n < 4; ++n)
    #pragma unroll
    for (int r = 0; r < 4; ++r) {
      int i = wave*16 + lq*4 + r;
      ctx[((size_t)b*SEQ + qs + i)*D_MODEL + h*DK + n*16 + l15] = oacc[n][r];
    }
}

// ---------------- LayerNorm (one wave per row, in-place safe) --------------
__global__ __launch_bounds__(256)
void ln_kernel(const float* __restrict__ in, const float* __restrict__ g,
               const float* __restrict__ bb, float* __restrict__ out)
{
  const int row = blockIdx.x*4 + (threadIdx.x >> 6);
  const int lane = threadIdx.x & 63;
  const float* p = in + (size_t)row*D_MODEL + lane*8;
  float4 v0 = *(const float4*)(p);
  float4 v1 = *(const float4*)(p + 4);
  float s  = v0.x+v0.y+v0.z+v0.w + v1.x+v1.y+v1.z+v1.w;
  float sq = v0.x*v0.x+v0.y*v0.y+v0.z*v0.z+v0.w*v0.w
           + v1.x*v1.x+v1.y*v1.y+v1.z*v1.z+v1.w*v1.w;
  #pragma unroll
  for (int off = 32; off; off >>= 1) { s += __shfl_xor(s, off); sq += __shfl_xor(sq, off); }
  const float mean = s * (1.0f/D_MODEL);
  const float var  = sq * (1.0f/D_MODEL) - mean*mean;
  const float rstd = rsqrtf(var + 1e-5f);
  float4 g0 = *(const float4*)(g + lane*8);
  float4 g1 = *(const float4*)(g + lane*8 + 4);
  float4 b0 = *(const float4*)(bb + lane*8);
  float4 b1 = *(const float4*)(bb + lane*8 + 4);
  float4 o0, o1;
  o0.x = (v0.x-mean)*rstd*g0.x + b0.x;
  o0.y = (v0.y-mean)*rstd*g0.y + b0.y;
  o0.z = (v0.z-mean)*rstd*g0.z + b0.z;
  o0.w = (v0.w-mean)*rstd*g0.w + b0.w;
  o1.x = (v1.x-mean)*rstd*g1.x + b1.x;
  o1.y = (v1.y-mean)*rstd*g1.y + b1.y;
  o1.z = (v1.z-mean)*rstd*g1.z + b1.z;
  o1.w = (v1.w-mean)*rstd*g1.w + b1.w;
  float* qo = out + (size_t)row*D_MODEL + lane*8;
  *(float4*)(qo)     = o0;
  *(float4*)(qo + 4) = o1;
}

extern "C" void kernel_launch(void* const* d_in, const int* in_sizes, int n_in,
                              void* d_out, int out_size, void* d_ws, size_t ws_size,
                              hipStream_t stream)
{
  (void)in_sizes; (void)n_in; (void)out_size; (void)ws_size;
  const float* x  = (const float*)d_in[0];
  const float* wq = (const float*)d_in[1];
  const float* bq = (const float*)d_in[2];
  const float* wk = (const float*)d_in[3];
  const float* bk = (const float*)d_in[4];
  const float* wv = (const float*)d_in[5];
  const float* bv = (const float*)d_in[6];
  const float* wo = (const float*)d_in[7];
  const float* bo = (const float*)d_in[8];
  const float* g1 = (const float*)d_in[9];
  const float* be1= (const float*)d_in[10];
  const float* w1 = (const float*)d_in[11];
  const float* b1 = (const float*)d_in[12];
  const float* w2 = (const float*)d_in[13];
  const float* b2 = (const float*)d_in[14];
  const float* g2 = (const float*)d_in[15];
  const float* be2= (const float*)d_in[16];

  const size_t RD = (size_t)ROWS * D_MODEL;
  u16*   qb   = (u16*)d_ws;           // bf16 [B,H,L,dk]
  u16*   kb   = qb + RD;
  u16*   vb   = kb + RD;
  float* ctx  = (float*)(vb + RD);    // f32 [B,L,D]
  float* hbuf = ctx + RD;             // f32 post-LN1
  u16*   ff1  = (u16*)d_ws;           // bf16 [ROWS,2048]; aliases qkv+ctx (dead by then)
  float* pre  = (float*)d_out;
  float* outp = (float*)d_out;

  dim3 blk(256);
  qkv_kernel<<<dim3(4,64,3), blk, 0, stream>>>(x, wq, bq, wk, bk, wv, bv, qb, kb, vb);
  attn_kernel<<<dim3(BATCH*NHEADS*32), blk, 0, stream>>>(qb, kb, vb, ctx);
  gemm_kernel<EP_RES, false><<<dim3(4,64), blk, 0, stream>>>(ctx, wo, bo, x, pre, 512, 512);
  ln_kernel<<<dim3(ROWS/4), blk, 0, stream>>>(pre, g1, be1, hbuf);
  gemm_kernel<EP_RELU, false><<<dim3(16,64), blk, 0, stream>>>(hbuf, w1, b1, nullptr, ff1, 512, 2048);
  gemm_kernel<EP_RES, true><<<dim3(4,64), blk, 0, stream>>>(ff1, w2, b2, hbuf, pre, 2048, 512);
  ln_kernel<<<dim3(ROWS/4), blk, 0, stream>>>(pre, g2, be2, outp);
}

// Round 9
// 268.323 us; speedup vs baseline: 1.9393x; 1.3174x over previous
//
#include <hip/hip_runtime.h>
#include <hip/hip_bf16.h>

#define D_MODEL 512
#define NHEADS 8
#define DK 64
#define WIN 64
#define SEQ 2048
#define BATCH 4
#define ROWS (BATCH*SEQ)

typedef unsigned short u16;
using bf16x8 = __attribute__((ext_vector_type(8))) short;
using f32x4  = __attribute__((ext_vector_type(4))) float;
using u16x4  = __attribute__((ext_vector_type(4))) unsigned short;

__device__ __forceinline__ u16 f2b(float f) {
  union { float f; unsigned u; } v; v.f = f;
  unsigned r = v.u + 0x7FFFu + ((v.u >> 16) & 1u);
  return (u16)(r >> 16);
}
__device__ __forceinline__ float b2f(u16 h) {
  union { unsigned u; float f; } v; v.u = ((unsigned)h) << 16; return v.f;
}

// async global->LDS, 16B per lane; LDS dest = uniform base + lane*16
__device__ __forceinline__ void gload16(const u16* g, u16* l) {
  __builtin_amdgcn_global_load_lds((const __attribute__((address_space(1))) void*)g,
                                   (__attribute__((address_space(3))) void*)l, 16, 0, 0);
}

// ============ pre-pass: weights f32[K][N] -> bf16 [N][K]; x -> bf16 ========
__global__ __launch_bounds__(256)
void prep_kernel(const float* __restrict__ wq, const float* __restrict__ wk,
                 const float* __restrict__ wv, const float* __restrict__ wo,
                 const float* __restrict__ w1, const float* __restrict__ w2,
                 const float* __restrict__ x,
                 u16* __restrict__ wqt, u16* __restrict__ wkt, u16* __restrict__ wvt,
                 u16* __restrict__ wot, u16* __restrict__ w1t, u16* __restrict__ w2t,
                 u16* __restrict__ xb)
{
  __shared__ u16 T[64][72];
  const int t = blockIdx.x;
  const float* src; u16* dst; int K, N, lt; bool tr = true;
  if (t < 256)      { int m = t >> 6; lt = t & 63;
                      src = m==0?wq:(m==1?wk:(m==2?wv:wo));
                      dst = m==0?wqt:(m==1?wkt:(m==2?wvt:wot));
                      K = 512; N = 512; }
  else if (t < 512) { src = w1; dst = w1t; K = 512;  N = 2048; lt = t-256; }
  else if (t < 768) { src = w2; dst = w2t; K = 2048; N = 512;  lt = t-512; }
  else              { src = x;  dst = xb;  K = 8192; N = 512;  lt = t-768; tr = false; }
  const int ntj = N >> 6;
  const int ti = lt / ntj, tj = lt - ti*ntj;  // ti: row-tile (K dim), tj: col-tile (N dim)
  const int tid = threadIdx.x;
  const int r = tid >> 2, c0 = (tid & 3) << 4;

  const float* sp = src + (size_t)(ti*64 + r)*N + tj*64 + c0;
  u16 h[16];
  #pragma unroll
  for (int u = 0; u < 4; ++u) {
    float4 v = *(const float4*)(sp + u*4);
    h[u*4+0]=f2b(v.x); h[u*4+1]=f2b(v.y); h[u*4+2]=f2b(v.z); h[u*4+3]=f2b(v.w);
  }
  if (!tr) {
    u16* dp = dst + (size_t)(ti*64 + r)*N + tj*64 + c0;
    *(bf16x8*)(dp)     = *(bf16x8*)&h[0];
    *(bf16x8*)(dp + 8) = *(bf16x8*)&h[8];
    return;
  }
  #pragma unroll
  for (int u = 0; u < 16; ++u) T[r][c0+u] = h[u];
  __syncthreads();
  u16 o[16];
  #pragma unroll
  for (int u = 0; u < 16; ++u) o[u] = T[c0+u][r];
  u16* dp = dst + (size_t)(tj*64 + r)*K + ti*64 + c0;
  *(bf16x8*)(dp)     = *(bf16x8*)&o[0];
  *(bf16x8*)(dp + 8) = *(bf16x8*)&o[8];
}

// ============ GEMM mainloop (m97 structure): A[M,K] bf16, Bt[N,K] bf16 =====
// 128x128 tile, BK=32, 4 waves, linear LDS [128][32], global_load_lds x16B.
__device__ __forceinline__ void mainloop_bt(
    const u16* __restrict__ A, const u16* __restrict__ Bt, int K,
    int m0, int n0, int tid, f32x4 (&acc)[4][4], u16* Asl, u16* Bsl)
{
  const int lane = tid & 63, wave = tid >> 6;
  const int wr = wave >> 1, wc = wave & 1;
  const int l15 = lane & 15, lq = lane >> 4;
  const int ar = lane >> 2;            // 0..15: row within 16-row issue group
  const int ac = (lane & 3) << 3;      // col (shorts): 0,8,16,24

  const u16* ag0 = A  + (size_t)(m0 + wave*32 + ar)*K + ac;
  const u16* bg0 = Bt + (size_t)(n0 + wave*32 + ar)*K + ac;
  u16* const aslw = Asl + wave*1024;   // wave-uniform LDS base (shorts)
  u16* const bslw = Bsl + wave*1024;

  for (int k0 = 0; k0 < K; k0 += 32) {
    __syncthreads();                   // prev-iter LDS reads done
    gload16(ag0 + k0,          aslw);
    gload16(ag0 + k0 + 16*K,   aslw + 512);
    gload16(bg0 + k0,          bslw);
    gload16(bg0 + k0 + 16*K,   bslw + 512);
    __syncthreads();                   // drains vmcnt(0): tiles ready

    bf16x8 af[4], bfr[4];
    #pragma unroll
    for (int m = 0; m < 4; ++m)
      af[m] = *(const bf16x8*)(&Asl[(wr*64 + m*16 + l15)*32 + lq*8]);
    #pragma unroll
    for (int n = 0; n < 4; ++n)
      bfr[n] = *(const bf16x8*)(&Bsl[(wc*64 + n*16 + l15)*32 + lq*8]);
    #pragma unroll
    for (int m = 0; m < 4; ++m)
      #pragma unroll
      for (int n = 0; n < 4; ++n)
        acc[m][n] = __builtin_amdgcn_mfma_f32_16x16x32_bf16(af[m], bfr[n], acc[m][n], 0, 0, 0);
  }
}

// ---------------- fused QKV: grid.z selects (Wt, bias, out) ----------------
__global__ __launch_bounds__(256)
void qkv_kernel(const u16* __restrict__ xb,
                const u16* __restrict__ wqt, const float* __restrict__ bq,
                const u16* __restrict__ wkt, const float* __restrict__ bk,
                const u16* __restrict__ wvt, const float* __restrict__ bv,
                u16* __restrict__ qo, u16* __restrict__ ko, u16* __restrict__ vo)
{
  __shared__ __align__(16) u16 Asl[128*32];
  __shared__ __align__(16) u16 Bsl[128*32];
  const u16* Wt; const float* bias; u16* out;
  if (blockIdx.z == 0)      { Wt = wqt; bias = bq; out = qo; }
  else if (blockIdx.z == 1) { Wt = wkt; bias = bk; out = ko; }
  else                      { Wt = wvt; bias = bv; out = vo; }

  const int tid = threadIdx.x;
  const int lane = tid & 63, wave = tid >> 6;
  const int wr = wave >> 1, wc = wave & 1;
  const int l15 = lane & 15, lq = lane >> 4;
  const int m0 = blockIdx.y * 128, n0 = blockIdx.x * 128;

  f32x4 acc[4][4] = {};
  mainloop_bt(xb, Wt, 512, m0, n0, tid, acc, Asl, Bsl);

  #pragma unroll
  for (int n = 0; n < 4; ++n) {
    const int col = n0 + wc*64 + n*16 + l15;
    const float bv2 = bias[col];
    const int h = col >> 6, d = col & 63;
    #pragma unroll
    for (int m = 0; m < 4; ++m)
      #pragma unroll
      for (int j = 0; j < 4; ++j) {
        const int row = m0 + wr*64 + m*16 + lq*4 + j;
        const int b = row >> 11, l = row & (SEQ-1);
        out[(((size_t)(b*NHEADS + h))*SEQ + l)*DK + d] = f2b(acc[m][n][j] + bv2);
      }
  }
}

// ---------------- generic GEMM with epilogue -------------------------------
#define EP_RES  1   // f32 out = acc + bias + resid
#define EP_RELU 2   // bf16 out = relu(acc + bias)

template<int EP>
__global__ __launch_bounds__(256)
void gemm_bt(const u16* __restrict__ A, const u16* __restrict__ Bt,
             const float* __restrict__ bias, const float* __restrict__ resid,
             void* __restrict__ out_, int K, int N)
{
  __shared__ __align__(16) u16 Asl[128*32];
  __shared__ __align__(16) u16 Bsl[128*32];

  const int tid = threadIdx.x;
  const int lane = tid & 63, wave = tid >> 6;
  const int wr = wave >> 1, wc = wave & 1;
  const int l15 = lane & 15, lq = lane >> 4;
  const int m0 = blockIdx.y * 128, n0 = blockIdx.x * 128;

  f32x4 acc[4][4] = {};
  mainloop_bt(A, Bt, K, m0, n0, tid, acc, Asl, Bsl);

  #pragma unroll
  for (int n = 0; n < 4; ++n) {
    const int col = n0 + wc*64 + n*16 + l15;
    const float bv2 = bias[col];
    #pragma unroll
    for (int m = 0; m < 4; ++m)
      #pragma unroll
      for (int j = 0; j < 4; ++j) {
        const int row = m0 + wr*64 + m*16 + lq*4 + j;
        const size_t o = (size_t)row*N + col;
        float val = acc[m][n][j] + bv2;
        if (EP == EP_RES)  ((float*)out_)[o] = val + resid[o];
        else               ((u16*)out_)[o]   = f2b(fmaxf(val, 0.0f));
      }
  }
}

// ================= MFMA sliding-window attention ===========================
__global__ __launch_bounds__(256)
void attn_kernel(const u16* __restrict__ q, const u16* __restrict__ k,
                 const u16* __restrict__ v, u16* __restrict__ ctx)
{
  __shared__ __align__(16) u16 Ksl[192*40];     // K rows [j][40]
  __shared__ __align__(16) u16 Vt[64*200];      // V^T rows [d][200], swizzled
  __shared__ __align__(16) u16 Pl[4][16*200];   // per-wave P rows [i][200]

  const int bid = blockIdx.x;
  const int t = bid & 31, h = (bid >> 5) & 7, b = bid >> 8;
  const int qs = t*64;
  const int ks0 = max(0, qs - WIN);
  const int ks1 = min(SEQ, qs + 64 + WIN);
  const int span = ks1 - ks0;                   // 128..192

  const size_t hoff = ((size_t)(b*NHEADS + h))*SEQ*DK;
  const u16* kh = k + hoff;
  const u16* vh = v + hoff;
  const int tid = threadIdx.x;

  #pragma unroll
  for (int i = 0; i < 6; ++i) {
    int e = tid + i*256;
    int r = e >> 3, c8 = (e & 7) << 3;
    bf16x8 val = {};
    if (r < span) val = *(const bf16x8*)(kh + (size_t)(ks0+r)*DK + c8);
    *(bf16x8*)(&Ksl[r*40 + c8]) = val;
  }
  #pragma unroll
  for (int i = 0; i < 12; ++i) {
    int e = tid + i*256;
    int j = e >> 4, d4 = (e & 15) << 2;
    u16x4 val{};
    if (j < span) val = *(const u16x4*)(vh + (size_t)(ks0+j)*DK + d4);
    #pragma unroll
    for (int u = 0; u < 4; ++u) {
      int d = d4 + u;
      int col = ((((j >> 3) ^ ((d >> 2) & 7)) << 3) | (j & 7));
      Vt[d*200 + col] = (u16)val[u];
    }
  }
  __syncthreads();

  const int wave = tid >> 6, lane = tid & 63;
  const int lq = lane >> 4, l15 = lane & 15;

  const u16* qrow = q + hoff + (size_t)(qs + wave*16 + l15)*DK;
  const bf16x8 qf0 = *(const bf16x8*)(qrow + lq*8);
  const bf16x8 qf1 = *(const bf16x8*)(qrow + 32 + lq*8);

  f32x4 sacc[12];
  #pragma unroll
  for (int m = 0; m < 12; ++m) sacc[m] = f32x4{0.f,0.f,0.f,0.f};
  #pragma unroll
  for (int m = 0; m < 12; ++m) {
    const u16* kr = &Ksl[(m*16 + l15)*40];
    bf16x8 ka0 = *(const bf16x8*)(kr + lq*8);
    bf16x8 ka1 = *(const bf16x8*)(kr + 32 + lq*8);
    sacc[m] = __builtin_amdgcn_mfma_f32_16x16x32_bf16(ka0, qf0, sacc[m], 0, 0, 0);
    sacc[m] = __builtin_amdgcn_mfma_f32_16x16x32_bf16(ka1, qf1, sacc[m], 0, 0, 0);
  }

  const int ig = qs + wave*16 + l15;
  float mx = -3.0e38f;
  #pragma unroll
  for (int m = 0; m < 12; ++m)
    #pragma unroll
    for (int r = 0; r < 4; ++r) {
      int jg = ks0 + m*16 + lq*4 + r;
      bool ok = (jg < ks1) && (jg >= ig - WIN) && (jg <= ig + WIN);
      float sv = ok ? sacc[m][r]*0.125f : -3.0e38f;
      sacc[m][r] = sv;
      mx = fmaxf(mx, sv);
    }
  mx = fmaxf(mx, __shfl_xor(mx, 16));
  mx = fmaxf(mx, __shfl_xor(mx, 32));
  float sum = 0.f;
  #pragma unroll
  for (int m = 0; m < 12; ++m)
    #pragma unroll
    for (int r = 0; r < 4; ++r) {
      float p = __expf(sacc[m][r] - mx);
      sacc[m][r] = p;
      sum += p;
    }
  sum += __shfl_xor(sum, 16);
  sum += __shfl_xor(sum, 32);
  const float inv = 1.0f / sum;

  u16* pw = &Pl[wave][0];
  #pragma unroll
  for (int m = 0; m < 12; ++m) {
    unsigned lo = (unsigned)f2b(sacc[m][0]*inv) | ((unsigned)f2b(sacc[m][1]*inv) << 16);
    unsigned hi = (unsigned)f2b(sacc[m][2]*inv) | ((unsigned)f2b(sacc[m][3]*inv) << 16);
    uint2 pk = make_uint2(lo, hi);
    *(uint2*)(&pw[l15*200 + m*16 + lq*4]) = pk;
  }

  f32x4 oacc[4] = {};
  #pragma unroll
  for (int kst = 0; kst < 6; ++kst) {
    bf16x8 pa = *(const bf16x8*)(&pw[l15*200 + kst*32 + lq*8]);
    #pragma unroll
    for (int n = 0; n < 4; ++n) {
      int d = n*16 + l15;
      int col = (((kst*4 + lq) ^ ((d >> 2) & 7)) << 3);
      bf16x8 vb = *(const bf16x8*)(&Vt[d*200 + col]);
      oacc[n] = __builtin_amdgcn_mfma_f32_16x16x32_bf16(pa, vb, oacc[n], 0, 0, 0);
    }
  }

  #pragma unroll
  for (int n = 0; n < 4; ++n)
    #pragma unroll
    for (int r = 0; r < 4; ++r) {
      int i = wave*16 + lq*4 + r;
      ctx[((size_t)b*SEQ + qs + i)*D_MODEL + h*DK + n*16 + l15] = f2b(oacc[n][r]);
    }
}

// ---------------- LayerNorm; optional bf16 mirror --------------------------
template<bool WB16>
__global__ __launch_bounds__(256)
void ln_kernel(const float* __restrict__ in, const float* __restrict__ g,
               const float* __restrict__ bb, float* __restrict__ out,
               u16* __restrict__ out16)
{
  const int row = blockIdx.x*4 + (threadIdx.x >> 6);
  const int lane = threadIdx.x & 63;
  const float* p = in + (size_t)row*D_MODEL + lane*8;
  float4 v0 = *(const float4*)(p);
  float4 v1 = *(const float4*)(p + 4);
  float s  = v0.x+v0.y+v0.z+v0.w + v1.x+v1.y+v1.z+v1.w;
  float sq = v0.x*v0.x+v0.y*v0.y+v0.z*v0.z+v0.w*v0.w
           + v1.x*v1.x+v1.y*v1.y+v1.z*v1.z+v1.w*v1.w;
  #pragma unroll
  for (int off = 32; off; off >>= 1) { s += __shfl_xor(s, off); sq += __shfl_xor(sq, off); }
  const float mean = s * (1.0f/D_MODEL);
  const float var  = sq * (1.0f/D_MODEL) - mean*mean;
  const float rstd = rsqrtf(var + 1e-5f);
  float4 g0 = *(const float4*)(g + lane*8);
  float4 g1 = *(const float4*)(g + lane*8 + 4);
  float4 b0 = *(const float4*)(bb + lane*8);
  float4 b1 = *(const float4*)(bb + lane*8 + 4);
  float4 o0, o1;
  o0.x = (v0.x-mean)*rstd*g0.x + b0.x;
  o0.y = (v0.y-mean)*rstd*g0.y + b0.y;
  o0.z = (v0.z-mean)*rstd*g0.z + b0.z;
  o0.w = (v0.w-mean)*rstd*g0.w + b0.w;
  o1.x = (v1.x-mean)*rstd*g1.x + b1.x;
  o1.y = (v1.y-mean)*rstd*g1.y + b1.y;
  o1.z = (v1.z-mean)*rstd*g1.z + b1.z;
  o1.w = (v1.w-mean)*rstd*g1.w + b1.w;
  float* qo = out + (size_t)row*D_MODEL + lane*8;
  *(float4*)(qo)     = o0;
  *(float4*)(qo + 4) = o1;
  if (WB16) {
    u16 hh[8];
    hh[0]=f2b(o0.x); hh[1]=f2b(o0.y); hh[2]=f2b(o0.z); hh[3]=f2b(o0.w);
    hh[4]=f2b(o1.x); hh[5]=f2b(o1.y); hh[6]=f2b(o1.z); hh[7]=f2b(o1.w);
    *(bf16x8*)(out16 + (size_t)row*D_MODEL + lane*8) = *(bf16x8*)&hh[0];
  }
}

extern "C" void kernel_launch(void* const* d_in, const int* in_sizes, int n_in,
                              void* d_out, int out_size, void* d_ws, size_t ws_size,
                              hipStream_t stream)
{
  (void)in_sizes; (void)n_in; (void)out_size; (void)ws_size;
  const float* x  = (const float*)d_in[0];
  const float* wq = (const float*)d_in[1];
  const float* bq = (const float*)d_in[2];
  const float* wk = (const float*)d_in[3];
  const float* bk = (const float*)d_in[4];
  const float* wv = (const float*)d_in[5];
  const float* bv = (const float*)d_in[6];
  const float* wo = (const float*)d_in[7];
  const float* bo = (const float*)d_in[8];
  const float* g1 = (const float*)d_in[9];
  const float* be1= (const float*)d_in[10];
  const float* w1 = (const float*)d_in[11];
  const float* b1 = (const float*)d_in[12];
  const float* w2 = (const float*)d_in[13];
  const float* b2 = (const float*)d_in[14];
  const float* g2 = (const float*)d_in[15];
  const float* be2= (const float*)d_in[16];

  const size_t RD = (size_t)ROWS * D_MODEL;   // 4.19M
  u16* W = (u16*)d_ws;
  u16*   xb   = W;
  u16*   qb   = W + RD;
  u16*   kb   = W + 2*RD;
  u16*   vb   = W + 3*RD;
  u16*   ctxb = W + 4*RD;
  u16*   hb16 = W + 5*RD;
  float* hbuf = (float*)(W + 6*RD);           // RD floats = 2RD u16
  u16*   wqt  = W + 8*RD;
  u16*   wkt  = wqt + 512*512;
  u16*   wvt  = wkt + 512*512;
  u16*   wot  = wvt + 512*512;
  u16*   w1t  = wot + 512*512;                // [2048][512]
  u16*   w2t  = w1t + 512*2048;               // [512][2048]
  u16*   ff1  = qb;                           // aliases qb..ctxb (4*RD = ROWS*2048)
  float* pre  = (float*)d_out;
  float* outp = (float*)d_out;

  dim3 blk(256);
  prep_kernel<<<dim3(1792), blk, 0, stream>>>(wq, wk, wv, wo, w1, w2, x,
                                              wqt, wkt, wvt, wot, w1t, w2t, xb);
  qkv_kernel<<<dim3(4,64,3), blk, 0, stream>>>(xb, wqt, bq, wkt, bk, wvt, bv, qb, kb, vb);
  attn_kernel<<<dim3(BATCH*NHEADS*32), blk, 0, stream>>>(qb, kb, vb, ctxb);
  gemm_bt<EP_RES><<<dim3(4,64), blk, 0, stream>>>(ctxb, wot, bo, x, pre, 512, 512);
  ln_kernel<true><<<dim3(ROWS/4), blk, 0, stream>>>(pre, g1, be1, hbuf, hb16);
  gemm_bt<EP_RELU><<<dim3(16,64), blk, 0, stream>>>(hb16, w1t, b1, nullptr, ff1, 512, 2048);
  gemm_bt<EP_RES><<<dim3(4,64), blk, 0, stream>>>(ff1, w2t, b2, hbuf, pre, 2048, 512);
  ln_kernel<false><<<dim3(ROWS/4), blk, 0, stream>>>(pre, g2, be2, outp, nullptr);
}

// Round 11
// 262.740 us; speedup vs baseline: 1.9805x; 1.0213x over previous
//
#include <hip/hip_runtime.h>
#include <hip/hip_bf16.h>

#define D_MODEL 512
#define NHEADS 8
#define DK 64
#define WIN 64
#define SEQ 2048
#define BATCH 4
#define ROWS (BATCH*SEQ)

typedef unsigned short u16;
using bf16x8 = __attribute__((ext_vector_type(8))) short;
using f32x4  = __attribute__((ext_vector_type(4))) float;
using u16x4  = __attribute__((ext_vector_type(4))) unsigned short;

__device__ __forceinline__ u16 f2b(float f) {
  union { float f; unsigned u; } v; v.f = f;
  unsigned r = v.u + 0x7FFFu + ((v.u >> 16) & 1u);
  return (u16)(r >> 16);
}
__device__ __forceinline__ float b2f(u16 h) {
  union { unsigned u; float f; } v; v.u = ((unsigned)h) << 16; return v.f;
}

// async global->LDS, 16B per lane; LDS dest = uniform base + lane*16
__device__ __forceinline__ void gload16(const u16* g, u16* l) {
  __builtin_amdgcn_global_load_lds((const __attribute__((address_space(1))) void*)g,
                                   (__attribute__((address_space(3))) void*)l, 16, 0, 0);
}

// ============ pre-pass: weights f32[K][N] -> bf16 [N][K]; x -> bf16 ========
__global__ __launch_bounds__(256)
void prep_kernel(const float* __restrict__ wq, const float* __restrict__ wk,
                 const float* __restrict__ wv, const float* __restrict__ wo,
                 const float* __restrict__ w1, const float* __restrict__ w2,
                 const float* __restrict__ x,
                 u16* __restrict__ wqt, u16* __restrict__ wkt, u16* __restrict__ wvt,
                 u16* __restrict__ wot, u16* __restrict__ w1t, u16* __restrict__ w2t,
                 u16* __restrict__ xb)
{
  __shared__ u16 T[64][72];
  const int t = blockIdx.x;
  const float* src; u16* dst; int K, N, lt; bool tr = true;
  if (t < 256)      { int m = t >> 6; lt = t & 63;
                      src = m==0?wq:(m==1?wk:(m==2?wv:wo));
                      dst = m==0?wqt:(m==1?wkt:(m==2?wvt:wot));
                      K = 512; N = 512; }
  else if (t < 512) { src = w1; dst = w1t; K = 512;  N = 2048; lt = t-256; }
  else if (t < 768) { src = w2; dst = w2t; K = 2048; N = 512;  lt = t-512; }
  else              { src = x;  dst = xb;  K = 8192; N = 512;  lt = t-768; tr = false; }
  const int ntj = N >> 6;
  const int ti = lt / ntj, tj = lt - ti*ntj;  // ti: row-tile (K dim), tj: col-tile (N dim)
  const int tid = threadIdx.x;
  const int r = tid >> 2, c0 = (tid & 3) << 4;

  const float* sp = src + (size_t)(ti*64 + r)*N + tj*64 + c0;
  u16 h[16];
  #pragma unroll
  for (int u = 0; u < 4; ++u) {
    float4 v = *(const float4*)(sp + u*4);
    h[u*4+0]=f2b(v.x); h[u*4+1]=f2b(v.y); h[u*4+2]=f2b(v.z); h[u*4+3]=f2b(v.w);
  }
  if (!tr) {
    u16* dp = dst + (size_t)(ti*64 + r)*N + tj*64 + c0;
    *(bf16x8*)(dp)     = *(bf16x8*)&h[0];
    *(bf16x8*)(dp + 8) = *(bf16x8*)&h[8];
    return;
  }
  #pragma unroll
  for (int u = 0; u < 16; ++u) T[r][c0+u] = h[u];
  __syncthreads();
  u16 o[16];
  #pragma unroll
  for (int u = 0; u < 16; ++u) o[u] = T[c0+u][r];
  u16* dp = dst + (size_t)(tj*64 + r)*K + ti*64 + c0;
  *(bf16x8*)(dp)     = *(bf16x8*)&o[0];
  *(bf16x8*)(dp + 8) = *(bf16x8*)&o[8];
}

// ============ GEMM mainloop: 128x128 tile, BK=32, 2-phase dbuf =============
// Stage for tile t+1 issues BEFORE ds_read+MFMA of tile t; one barrier/step.
// The __syncthreads vmcnt(0) drain then waits on loads issued a full MFMA
// phase earlier (already landed) -> pipeline fills even at 1 block/CU.
__device__ __forceinline__ void mainloop_bt(
    const u16* __restrict__ A, const u16* __restrict__ Bt, int K,
    int m0, int n0, int tid, f32x4 (&acc)[4][4],
    u16 (*Asl)[128*32], u16 (*Bsl)[128*32])
{
  const int lane = tid & 63, wave = tid >> 6;
  const int wr = wave >> 1, wc = wave & 1;
  const int l15 = lane & 15, lq = lane >> 4;
  const int ar = lane >> 2;            // 0..15: row within 16-row issue group
  const int ac = (lane & 3) << 3;      // col (shorts): 0,8,16,24

  const u16* ag0 = A  + (size_t)(m0 + wave*32 + ar)*K + ac;
  const u16* bg0 = Bt + (size_t)(n0 + wave*32 + ar)*K + ac;

  auto stage = [&](int buf, int k0) {
    u16* aslw = &Asl[buf][wave*1024];  // wave-uniform LDS base
    u16* bslw = &Bsl[buf][wave*1024];
    gload16(ag0 + k0,        aslw);
    gload16(ag0 + k0 + 16*K, aslw + 512);
    gload16(bg0 + k0,        bslw);
    gload16(bg0 + k0 + 16*K, bslw + 512);
  };
  auto compute = [&](int buf) {
    bf16x8 af[4], bfr[4];
    #pragma unroll
    for (int m = 0; m < 4; ++m)
      af[m] = *(const bf16x8*)(&Asl[buf][(wr*64 + m*16 + l15)*32 + lq*8]);
    #pragma unroll
    for (int n = 0; n < 4; ++n)
      bfr[n] = *(const bf16x8*)(&Bsl[buf][(wc*64 + n*16 + l15)*32 + lq*8]);
    #pragma unroll
    for (int m = 0; m < 4; ++m)
      #pragma unroll
      for (int n = 0; n < 4; ++n)
        acc[m][n] = __builtin_amdgcn_mfma_f32_16x16x32_bf16(af[m], bfr[n], acc[m][n], 0, 0, 0);
  };

  stage(0, 0);
  __syncthreads();                     // tile 0 landed
  int cur = 0;
  const int nt = K >> 5;
  for (int t = 0; t < nt - 1; ++t) {
    stage(cur ^ 1, (t + 1) << 5);      // prefetch next tile (overlaps compute)
    compute(cur);
    __syncthreads();                   // drain prefetch + sync LDS reads
    cur ^= 1;
  }
  compute(cur);
}

// ---------------- fused QKV: grid.z selects (Wt, bias, out) ----------------
// grid (m=64, n=4, z=3): linear id = m + 64n + 256z -> XCD = m%8 for all n,z
// sharing the same A-panel (xb rows) -> A fetched ~once per XCD L2.
__global__ __launch_bounds__(256)
void qkv_kernel(const u16* __restrict__ xb,
                const u16* __restrict__ wqt, const float* __restrict__ bq,
                const u16* __restrict__ wkt, const float* __restrict__ bk,
                const u16* __restrict__ wvt, const float* __restrict__ bv,
                u16* __restrict__ qo, u16* __restrict__ ko, u16* __restrict__ vo)
{
  __shared__ __align__(16) u16 Asl[2][128*32];
  __shared__ __align__(16) u16 Bsl[2][128*32];
  const u16* Wt; const float* bias; u16* out;
  if (blockIdx.z == 0)      { Wt = wqt; bias = bq; out = qo; }
  else if (blockIdx.z == 1) { Wt = wkt; bias = bk; out = ko; }
  else                      { Wt = wvt; bias = bv; out = vo; }

  const int tid = threadIdx.x;
  const int lane = tid & 63, wave = tid >> 6;
  const int wr = wave >> 1, wc = wave & 1;
  const int l15 = lane & 15, lq = lane >> 4;
  const int m0 = blockIdx.x * 128, n0 = blockIdx.y * 128;

  f32x4 acc[4][4] = {};
  mainloop_bt(xb, Wt, 512, m0, n0, tid, acc, Asl, Bsl);

  #pragma unroll
  for (int n = 0; n < 4; ++n) {
    const int col = n0 + wc*64 + n*16 + l15;
    const float bv2 = bias[col];
    const int h = col >> 6, d = col & 63;
    #pragma unroll
    for (int m = 0; m < 4; ++m)
      #pragma unroll
      for (int j = 0; j < 4; ++j) {
        const int row = m0 + wr*64 + m*16 + lq*4 + j;
        const int b = row >> 11, l = row & (SEQ-1);
        out[(((size_t)(b*NHEADS + h))*SEQ + l)*DK + d] = f2b(acc[m][n][j] + bv2);
      }
  }
}

// ---------------- generic GEMM with epilogue -------------------------------
#define EP_RES  1   // f32 out = acc + bias + resid
#define EP_RELU 2   // bf16 out = relu(acc + bias)

template<int EP>
__global__ __launch_bounds__(256)
void gemm_bt(const u16* __restrict__ A, const u16* __restrict__ Bt,
             const float* __restrict__ bias, const float* __restrict__ resid,
             void* __restrict__ out_, int K, int N)
{
  __shared__ __align__(16) u16 Asl[2][128*32];
  __shared__ __align__(16) u16 Bsl[2][128*32];

  const int tid = threadIdx.x;
  const int lane = tid & 63, wave = tid >> 6;
  const int wr = wave >> 1, wc = wave & 1;
  const int l15 = lane & 15, lq = lane >> 4;
  const int m0 = blockIdx.x * 128, n0 = blockIdx.y * 128;

  f32x4 acc[4][4] = {};
  mainloop_bt(A, Bt, K, m0, n0, tid, acc, Asl, Bsl);

  #pragma unroll
  for (int n = 0; n < 4; ++n) {
    const int col = n0 + wc*64 + n*16 + l15;
    const float bv2 = bias[col];
    #pragma unroll
    for (int m = 0; m < 4; ++m)
      #pragma unroll
      for (int j = 0; j < 4; ++j) {
        const int row = m0 + wr*64 + m*16 + lq*4 + j;
        const size_t o = (size_t)row*N + col;
        float val = acc[m][n][j] + bv2;
        if (EP == EP_RES)  ((float*)out_)[o] = val + resid[o];
        else               ((u16*)out_)[o]   = f2b(fmaxf(val, 0.0f));
      }
  }
}

// ================= MFMA sliding-window attention ===========================
__global__ __launch_bounds__(256)
void attn_kernel(const u16* __restrict__ q, const u16* __restrict__ k,
                 const u16* __restrict__ v, u16* __restrict__ ctx)
{
  __shared__ __align__(16) u16 Ksl[192*40];     // K rows [j][40]
  __shared__ __align__(16) u16 Vt[64*200];      // V^T rows [d][200], swizzled
  __shared__ __align__(16) u16 Pl[4][16*200];   // per-wave P rows [i][200]

  const int bid = blockIdx.x;
  const int t = bid & 31, h = (bid >> 5) & 7, b = bid >> 8;
  const int qs = t*64;
  const int ks0 = max(0, qs - WIN);
  const int ks1 = min(SEQ, qs + 64 + WIN);
  const int span = ks1 - ks0;                   // 128..192

  const size_t hoff = ((size_t)(b*NHEADS + h))*SEQ*DK;
  const u16* kh = k + hoff;
  const u16* vh = v + hoff;
  const int tid = threadIdx.x;

  #pragma unroll
  for (int i = 0; i < 6; ++i) {
    int e = tid + i*256;
    int r = e >> 3, c8 = (e & 7) << 3;
    bf16x8 val = {};
    if (r < span) val = *(const bf16x8*)(kh + (size_t)(ks0+r)*DK + c8);
    *(bf16x8*)(&Ksl[r*40 + c8]) = val;
  }
  #pragma unroll
  for (int i = 0; i < 12; ++i) {
    int e = tid + i*256;
    int j = e >> 4, d4 = (e & 15) << 2;
    u16x4 val{};
    if (j < span) val = *(const u16x4*)(vh + (size_t)(ks0+j)*DK + d4);
    #pragma unroll
    for (int u = 0; u < 4; ++u) {
      int d = d4 + u;
      int col = ((((j >> 3) ^ ((d >> 2) & 7)) << 3) | (j & 7));
      Vt[d*200 + col] = (u16)val[u];
    }
  }
  __syncthreads();

  const int wave = tid >> 6, lane = tid & 63;
  const int lq = lane >> 4, l15 = lane & 15;

  const u16* qrow = q + hoff + (size_t)(qs + wave*16 + l15)*DK;
  const bf16x8 qf0 = *(const bf16x8*)(qrow + lq*8);
  const bf16x8 qf1 = *(const bf16x8*)(qrow + 32 + lq*8);

  f32x4 sacc[12];
  #pragma unroll
  for (int m = 0; m < 12; ++m) sacc[m] = f32x4{0.f,0.f,0.f,0.f};
  #pragma unroll
  for (int m = 0; m < 12; ++m) {
    const u16* kr = &Ksl[(m*16 + l15)*40];
    bf16x8 ka0 = *(const bf16x8*)(kr + lq*8);
    bf16x8 ka1 = *(const bf16x8*)(kr + 32 + lq*8);
    sacc[m] = __builtin_amdgcn_mfma_f32_16x16x32_bf16(ka0, qf0, sacc[m], 0, 0, 0);
    sacc[m] = __builtin_amdgcn_mfma_f32_16x16x32_bf16(ka1, qf1, sacc[m], 0, 0, 0);
  }

  const int ig = qs + wave*16 + l15;
  float mx = -3.0e38f;
  #pragma unroll
  for (int m = 0; m < 12; ++m)
    #pragma unroll
    for (int r = 0; r < 4; ++r) {
      int jg = ks0 + m*16 + lq*4 + r;
      bool ok = (jg < ks1) && (jg >= ig - WIN) && (jg <= ig + WIN);
      float sv = ok ? sacc[m][r]*0.125f : -3.0e38f;
      sacc[m][r] = sv;
      mx = fmaxf(mx, sv);
    }
  mx = fmaxf(mx, __shfl_xor(mx, 16));
  mx = fmaxf(mx, __shfl_xor(mx, 32));
  float sum = 0.f;
  #pragma unroll
  for (int m = 0; m < 12; ++m)
    #pragma unroll
    for (int r = 0; r < 4; ++r) {
      float p = __expf(sacc[m][r] - mx);
      sacc[m][r] = p;
      sum += p;
    }
  sum += __shfl_xor(sum, 16);
  sum += __shfl_xor(sum, 32);
  const float inv = 1.0f / sum;

  u16* pw = &Pl[wave][0];
  #pragma unroll
  for (int m = 0; m < 12; ++m) {
    unsigned lo = (unsigned)f2b(sacc[m][0]*inv) | ((unsigned)f2b(sacc[m][1]*inv) << 16);
    unsigned hi = (unsigned)f2b(sacc[m][2]*inv) | ((unsigned)f2b(sacc[m][3]*inv) << 16);
    uint2 pk = make_uint2(lo, hi);
    *(uint2*)(&pw[l15*200 + m*16 + lq*4]) = pk;
  }

  f32x4 oacc[4] = {};
  #pragma unroll
  for (int kst = 0; kst < 6; ++kst) {
    bf16x8 pa = *(const bf16x8*)(&pw[l15*200 + kst*32 + lq*8]);
    #pragma unroll
    for (int n = 0; n < 4; ++n) {
      int d = n*16 + l15;
      int col = (((kst*4 + lq) ^ ((d >> 2) & 7)) << 3);
      bf16x8 vb = *(const bf16x8*)(&Vt[d*200 + col]);
      oacc[n] = __builtin_amdgcn_mfma_f32_16x16x32_bf16(pa, vb, oacc[n], 0, 0, 0);
    }
  }

  #pragma unroll
  for (int n = 0; n < 4; ++n)
    #pragma unroll
    for (int r = 0; r < 4; ++r) {
      int i = wave*16 + lq*4 + r;
      ctx[((size_t)b*SEQ + qs + i)*D_MODEL + h*DK + n*16 + l15] = f2b(oacc[n][r]);
    }
}

// ---------------- LayerNorm; optional bf16 mirror --------------------------
template<bool WB16>
__global__ __launch_bounds__(256)
void ln_kernel(const float* __restrict__ in, const float* __restrict__ g,
               const float* __restrict__ bb, float* __restrict__ out,
               u16* __restrict__ out16)
{
  const int row = blockIdx.x*4 + (threadIdx.x >> 6);
  const int lane = threadIdx.x & 63;
  const float* p = in + (size_t)row*D_MODEL + lane*8;
  float4 v0 = *(const float4*)(p);
  float4 v1 = *(const float4*)(p + 4);
  float s  = v0.x+v0.y+v0.z+v0.w + v1.x+v1.y+v1.z+v1.w;
  float sq = v0.x*v0.x+v0.y*v0.y+v0.z*v0.z+v0.w*v0.w
           + v1.x*v1.x+v1.y*v1.y+v1.z*v1.z+v1.w*v1.w;
  #pragma unroll
  for (int off = 32; off; off >>= 1) { s += __shfl_xor(s, off); sq += __shfl_xor(sq, off); }
  const float mean = s * (1.0f/D_MODEL);
  const float var  = sq * (1.0f/D_MODEL) - mean*mean;
  const float rstd = rsqrtf(var + 1e-5f);
  float4 g0 = *(const float4*)(g + lane*8);
  float4 g1 = *(const float4*)(g + lane*8 + 4);
  float4 b0 = *(const float4*)(bb + lane*8);
  float4 b1 = *(const float4*)(bb + lane*8 + 4);
  float4 o0, o1;
  o0.x = (v0.x-mean)*rstd*g0.x + b0.x;
  o0.y = (v0.y-mean)*rstd*g0.y + b0.y;
  o0.z = (v0.z-mean)*rstd*g0.z + b0.z;
  o0.w = (v0.w-mean)*rstd*g0.w + b0.w;
  o1.x = (v1.x-mean)*rstd*g1.x + b1.x;
  o1.y = (v1.y-mean)*rstd*g1.y + b1.y;
  o1.z = (v1.z-mean)*rstd*g1.z + b1.z;
  o1.w = (v1.w-mean)*rstd*g1.w + b1.w;
  float* qo = out + (size_t)row*D_MODEL + lane*8;
  *(float4*)(qo)     = o0;
  *(float4*)(qo + 4) = o1;
  if (WB16) {
    u16 hh[8];
    hh[0]=f2b(o0.x); hh[1]=f2b(o0.y); hh[2]=f2b(o0.z); hh[3]=f2b(o0.w);
    hh[4]=f2b(o1.x); hh[5]=f2b(o1.y); hh[6]=f2b(o1.z); hh[7]=f2b(o1.w);
    *(bf16x8*)(out16 + (size_t)row*D_MODEL + lane*8) = *(bf16x8*)&hh[0];
  }
}

extern "C" void kernel_launch(void* const* d_in, const int* in_sizes, int n_in,
                              void* d_out, int out_size, void* d_ws, size_t ws_size,
                              hipStream_t stream)
{
  (void)in_sizes; (void)n_in; (void)out_size; (void)ws_size;
  const float* x  = (const float*)d_in[0];
  const float* wq = (const float*)d_in[1];
  const float* bq = (const float*)d_in[2];
  const float* wk = (const float*)d_in[3];
  const float* bk = (const float*)d_in[4];
  const float* wv = (const float*)d_in[5];
  const float* bv = (const float*)d_in[6];
  const float* wo = (const float*)d_in[7];
  const float* bo = (const float*)d_in[8];
  const float* g1 = (const float*)d_in[9];
  const float* be1= (const float*)d_in[10];
  const float* w1 = (const float*)d_in[11];
  const float* b1 = (const float*)d_in[12];
  const float* w2 = (const float*)d_in[13];
  const float* b2 = (const float*)d_in[14];
  const float* g2 = (const float*)d_in[15];
  const float* be2= (const float*)d_in[16];

  const size_t RD = (size_t)ROWS * D_MODEL;   // 4.19M
  u16* W = (u16*)d_ws;
  u16*   xb   = W;
  u16*   qb   = W + RD;
  u16*   kb   = W + 2*RD;
  u16*   vb   = W + 3*RD;
  u16*   ctxb = W + 4*RD;
  u16*   hb16 = W + 5*RD;
  float* hbuf = (float*)(W + 6*RD);           // RD floats = 2RD u16
  u16*   wqt  = W + 8*RD;
  u16*   wkt  = wqt + 512*512;
  u16*   wvt  = wkt + 512*512;
  u16*   wot  = wvt + 512*512;
  u16*   w1t  = wot + 512*512;                // [2048][512]
  u16*   w2t  = w1t + 512*2048;               // [512][2048]
  u16*   ff1  = qb;                           // aliases qb..ctxb (4*RD = ROWS*2048)
  float* pre  = (float*)d_out;
  float* outp = (float*)d_out;

  dim3 blk(256);
  prep_kernel<<<dim3(1792), blk, 0, stream>>>(wq, wk, wv, wo, w1, w2, x,
                                              wqt, wkt, wvt, wot, w1t, w2t, xb);
  qkv_kernel<<<dim3(64,4,3), blk, 0, stream>>>(xb, wqt, bq, wkt, bk, wvt, bv, qb, kb, vb);
  attn_kernel<<<dim3(BATCH*NHEADS*32), blk, 0, stream>>>(qb, kb, vb, ctxb);
  gemm_bt<EP_RES><<<dim3(64,4), blk, 0, stream>>>(ctxb, wot, bo, x, pre, 512, 512);
  ln_kernel<true><<<dim3(ROWS/4), blk, 0, stream>>>(pre, g1, be1, hbuf, hb16);
  gemm_bt<EP_RELU><<<dim3(64,16), blk, 0, stream>>>(hb16, w1t, b1, nullptr, ff1, 512, 2048);
  gemm_bt<EP_RES><<<dim3(64,4), blk, 0, stream>>>(ff1, w2t, b2, hbuf, pre, 2048, 512);
  ln_kernel<false><<<dim3(ROWS/4), blk, 0, stream>>>(pre, g2, be2, outp, nullptr);
}

// Round 14
// 254.854 us; speedup vs baseline: 2.0418x; 1.0309x over previous
//
#include <hip/hip_runtime.h>
#include <hip/hip_bf16.h>

#define D_MODEL 512
#define NHEADS 8
#define DK 64
#define WIN 64
#define SEQ 2048
#define BATCH 4
#define ROWS (BATCH*SEQ)

typedef unsigned short u16;
using bf16x8 = __attribute__((ext_vector_type(8))) short;
using f32x4  = __attribute__((ext_vector_type(4))) float;
using u16x4  = __attribute__((ext_vector_type(4))) unsigned short;

__device__ __forceinline__ u16 f2b(float f) {
  union { float f; unsigned u; } v; v.f = f;
  unsigned r = v.u + 0x7FFFu + ((v.u >> 16) & 1u);
  return (u16)(r >> 16);
}
__device__ __forceinline__ float b2f(u16 h) {
  union { unsigned u; float f; } v; v.u = ((unsigned)h) << 16; return v.f;
}

// async global->LDS, 16B per lane; LDS dest = uniform base + lane*16
__device__ __forceinline__ void gload16(const u16* g, u16* l) {
  __builtin_amdgcn_global_load_lds((const __attribute__((address_space(1))) void*)g,
                                   (__attribute__((address_space(3))) void*)l, 16, 0, 0);
}

// ============ pre-pass: weights f32[K][N] -> bf16 [N][K]; x -> bf16 ========
__global__ __launch_bounds__(256)
void prep_kernel(const float* __restrict__ wq, const float* __restrict__ wk,
                 const float* __restrict__ wv, const float* __restrict__ wo,
                 const float* __restrict__ w1, const float* __restrict__ w2,
                 const float* __restrict__ x,
                 u16* __restrict__ wqt, u16* __restrict__ wkt, u16* __restrict__ wvt,
                 u16* __restrict__ wot, u16* __restrict__ w1t, u16* __restrict__ w2t,
                 u16* __restrict__ xb)
{
  __shared__ u16 T[64][72];
  const int t = blockIdx.x;
  const float* src; u16* dst; int K, N, lt; bool tr = true;
  if (t < 256)      { int m = t >> 6; lt = t & 63;
                      src = m==0?wq:(m==1?wk:(m==2?wv:wo));
                      dst = m==0?wqt:(m==1?wkt:(m==2?wvt:wot));
                      K = 512; N = 512; }
  else if (t < 512) { src = w1; dst = w1t; K = 512;  N = 2048; lt = t-256; }
  else if (t < 768) { src = w2; dst = w2t; K = 2048; N = 512;  lt = t-512; }
  else              { src = x;  dst = xb;  K = 8192; N = 512;  lt = t-768; tr = false; }
  const int ntj = N >> 6;
  const int ti = lt / ntj, tj = lt - ti*ntj;  // ti: row-tile (K dim), tj: col-tile (N dim)
  const int tid = threadIdx.x;
  const int r = tid >> 2, c0 = (tid & 3) << 4;

  const float* sp = src + (size_t)(ti*64 + r)*N + tj*64 + c0;
  u16 h[16];
  #pragma unroll
  for (int u = 0; u < 4; ++u) {
    float4 v = *(const float4*)(sp + u*4);
    h[u*4+0]=f2b(v.x); h[u*4+1]=f2b(v.y); h[u*4+2]=f2b(v.z); h[u*4+3]=f2b(v.w);
  }
  if (!tr) {
    u16* dp = dst + (size_t)(ti*64 + r)*N + tj*64 + c0;
    *(bf16x8*)(dp)     = *(bf16x8*)&h[0];
    *(bf16x8*)(dp + 8) = *(bf16x8*)&h[8];
    return;
  }
  #pragma unroll
  for (int u = 0; u < 16; ++u) T[r][c0+u] = h[u];
  __syncthreads();
  u16 o[16];
  #pragma unroll
  for (int u = 0; u < 16; ++u) o[u] = T[c0+u][r];
  u16* dp = dst + (size_t)(tj*64 + r)*K + ti*64 + c0;
  *(bf16x8*)(dp)     = *(bf16x8*)&o[0];
  *(bf16x8*)(dp + 8) = *(bf16x8*)&o[8];
}

// ============ GEMM mainloop: 64x128 tile, BK=32, 3-stage issue-ahead =======
// Smaller M-tile doubles grid -> >=2 blocks/CU; barrier drains are then
// covered by the co-resident block (m114 inter-block overlap).  Stage for
// tile t+2 issues right AFTER the barrier (race-free: barrier guarantees
// compute(t-1), the last reader of that buffer, has finished).
__device__ __forceinline__ void mainloop_bt(
    const u16* __restrict__ A, const u16* __restrict__ Bt, int K,
    int m0, int n0, int tid, f32x4 (&acc)[2][4],
    u16 (*Asl)[64*32], u16 (*Bsl)[128*32])
{
  const int lane = tid & 63, wave = tid >> 6;
  const int wr = wave >> 1, wc = wave & 1;
  const int l15 = lane & 15, lq = lane >> 4;
  const int ar = lane >> 2;            // 0..15: row within 16-row issue group
  const int ac = (lane & 3) << 3;      // col (shorts): 0,8,16,24

  const u16* ag0 = A  + (size_t)(m0 + wave*16 + ar)*K + ac;   // 16 rows/wave
  const u16* bg0 = Bt + (size_t)(n0 + wave*32 + ar)*K + ac;   // 32 rows/wave

  auto stage = [&](int buf, int k0) {
    u16* aslw = &Asl[buf][wave*512];   // wave-uniform LDS base (shorts)
    u16* bslw = &Bsl[buf][wave*1024];
    gload16(ag0 + k0,        aslw);
    gload16(bg0 + k0,        bslw);
    gload16(bg0 + k0 + 16*K, bslw + 512);
  };
  auto compute = [&](int buf) {
    bf16x8 af[2], bfr[4];
    #pragma unroll
    for (int m = 0; m < 2; ++m)
      af[m] = *(const bf16x8*)(&Asl[buf][(wr*32 + m*16 + l15)*32 + lq*8]);
    #pragma unroll
    for (int n = 0; n < 4; ++n)
      bfr[n] = *(const bf16x8*)(&Bsl[buf][(wc*64 + n*16 + l15)*32 + lq*8]);
    #pragma unroll
    for (int m = 0; m < 2; ++m)
      #pragma unroll
      for (int n = 0; n < 4; ++n)
        acc[m][n] = __builtin_amdgcn_mfma_f32_16x16x32_bf16(af[m], bfr[n], acc[m][n], 0, 0, 0);
  };

  const int nt = K >> 5;
  stage(0, 0);
  stage(1, 32);
  for (int t = 0; t < nt; ++t) {
    __syncthreads();                   // drains stage(t); compute(t-1) done
    if (t + 2 < nt) stage((t + 2) % 3, (t + 2) << 5);
    compute(t % 3);
  }
}

// ---------------- fused QKV: grid.z selects (Wt, bias, out) ----------------
// grid (m=128, n=4, z=3): linear id = m + 128n + 512z -> XCD = m%8 for all
// n,z sharing the same A-panel (xb rows) -> A panel L2-local per XCD.
__global__ __launch_bounds__(256)
void qkv_kernel(const u16* __restrict__ xb,
                const u16* __restrict__ wqt, const float* __restrict__ bq,
                const u16* __restrict__ wkt, const float* __restrict__ bk,
                const u16* __restrict__ wvt, const float* __restrict__ bv,
                u16* __restrict__ qo, u16* __restrict__ ko, u16* __restrict__ vo)
{
  __shared__ __align__(16) u16 Asl[3][64*32];
  __shared__ __align__(16) u16 Bsl[3][128*32];
  const u16* Wt; const float* bias; u16* out;
  if (blockIdx.z == 0)      { Wt = wqt; bias = bq; out = qo; }
  else if (blockIdx.z == 1) { Wt = wkt; bias = bk; out = ko; }
  else                      { Wt = wvt; bias = bv; out = vo; }

  const int tid = threadIdx.x;
  const int lane = tid & 63, wave = tid >> 6;
  const int wr = wave >> 1, wc = wave & 1;
  const int l15 = lane & 15, lq = lane >> 4;
  const int m0 = blockIdx.x * 64, n0 = blockIdx.y * 128;

  f32x4 acc[2][4] = {};
  mainloop_bt(xb, Wt, 512, m0, n0, tid, acc, Asl, Bsl);

  #pragma unroll
  for (int n = 0; n < 4; ++n) {
    const int col = n0 + wc*64 + n*16 + l15;
    const float bv2 = bias[col];
    const int h = col >> 6, d = col & 63;
    #pragma unroll
    for (int m = 0; m < 2; ++m)
      #pragma unroll
      for (int j = 0; j < 4; ++j) {
        const int row = m0 + wr*32 + m*16 + lq*4 + j;
        const int b = row >> 11, l = row & (SEQ-1);
        out[(((size_t)(b*NHEADS + h))*SEQ + l)*DK + d] = f2b(acc[m][n][j] + bv2);
      }
  }
}

// ---------------- generic GEMM with epilogue -------------------------------
#define EP_RES  1   // f32 out = acc + bias + resid
#define EP_RELU 2   // bf16 out = relu(acc + bias)

template<int EP>
__global__ __launch_bounds__(256)
void gemm_bt(const u16* __restrict__ A, const u16* __restrict__ Bt,
             const float* __restrict__ bias, const float* __restrict__ resid,
             void* __restrict__ out_, int K, int N)
{
  __shared__ __align__(16) u16 Asl[3][64*32];
  __shared__ __align__(16) u16 Bsl[3][128*32];

  const int tid = threadIdx.x;
  const int lane = tid & 63, wave = tid >> 6;
  const int wr = wave >> 1, wc = wave & 1;
  const int l15 = lane & 15, lq = lane >> 4;
  const int m0 = blockIdx.x * 64, n0 = blockIdx.y * 128;

  f32x4 acc[2][4] = {};
  mainloop_bt(A, Bt, K, m0, n0, tid, acc, Asl, Bsl);

  #pragma unroll
  for (int n = 0; n < 4; ++n) {
    const int col = n0 + wc*64 + n*16 + l15;
    const float bv2 = bias[col];
    #pragma unroll
    for (int m = 0; m < 2; ++m)
      #pragma unroll
      for (int j = 0; j < 4; ++j) {
        const int row = m0 + wr*32 + m*16 + lq*4 + j;
        const size_t o = (size_t)row*N + col;
        float val = acc[m][n][j] + bv2;
        if (EP == EP_RES)  ((float*)out_)[o] = val + resid[o];
        else               ((u16*)out_)[o]   = f2b(fmaxf(val, 0.0f));
      }
  }
}

// ================= MFMA sliding-window attention ===========================
__global__ __launch_bounds__(256)
void attn_kernel(const u16* __restrict__ q, const u16* __restrict__ k,
                 const u16* __restrict__ v, u16* __restrict__ ctx)
{
  __shared__ __align__(16) u16 Ksl[192*40];     // K rows [j][40]
  __shared__ __align__(16) u16 Vt[64*200];      // V^T rows [d][200], swizzled
  __shared__ __align__(16) u16 Pl[4][16*200];   // per-wave P rows [i][200]

  const int bid = blockIdx.x;
  const int t = bid & 31, h = (bid >> 5) & 7, b = bid >> 8;
  const int qs = t*64;
  const int ks0 = max(0, qs - WIN);
  const int ks1 = min(SEQ, qs + 64 + WIN);
  const int span = ks1 - ks0;                   // 128..192

  const size_t hoff = ((size_t)(b*NHEADS + h))*SEQ*DK;
  const u16* kh = k + hoff;
  const u16* vh = v + hoff;
  const int tid = threadIdx.x;

  #pragma unroll
  for (int i = 0; i < 6; ++i) {
    int e = tid + i*256;
    int r = e >> 3, c8 = (e & 7) << 3;
    bf16x8 val = {};
    if (r < span) val = *(const bf16x8*)(kh + (size_t)(ks0+r)*DK + c8);
    *(bf16x8*)(&Ksl[r*40 + c8]) = val;
  }
  #pragma unroll
  for (int i = 0; i < 12; ++i) {
    int e = tid + i*256;
    int j = e >> 4, d4 = (e & 15) << 2;
    u16x4 val{};
    if (j < span) val = *(const u16x4*)(vh + (size_t)(ks0+j)*DK + d4);
    #pragma unroll
    for (int u = 0; u < 4; ++u) {
      int d = d4 + u;
      int col = ((((j >> 3) ^ ((d >> 2) & 7)) << 3) | (j & 7));
      Vt[d*200 + col] = (u16)val[u];
    }
  }
  __syncthreads();

  const int wave = tid >> 6, lane = tid & 63;
  const int lq = lane >> 4, l15 = lane & 15;

  const u16* qrow = q + hoff + (size_t)(qs + wave*16 + l15)*DK;
  const bf16x8 qf0 = *(const bf16x8*)(qrow + lq*8);
  const bf16x8 qf1 = *(const bf16x8*)(qrow + 32 + lq*8);

  f32x4 sacc[12];
  #pragma unroll
  for (int m = 0; m < 12; ++m) sacc[m] = f32x4{0.f,0.f,0.f,0.f};
  #pragma unroll
  for (int m = 0; m < 12; ++m) {
    const u16* kr = &Ksl[(m*16 + l15)*40];
    bf16x8 ka0 = *(const bf16x8*)(kr + lq*8);
    bf16x8 ka1 = *(const bf16x8*)(kr + 32 + lq*8);
    sacc[m] = __builtin_amdgcn_mfma_f32_16x16x32_bf16(ka0, qf0, sacc[m], 0, 0, 0);
    sacc[m] = __builtin_amdgcn_mfma_f32_16x16x32_bf16(ka1, qf1, sacc[m], 0, 0, 0);
  }

  const int ig = qs + wave*16 + l15;
  float mx = -3.0e38f;
  #pragma unroll
  for (int m = 0; m < 12; ++m)
    #pragma unroll
    for (int r = 0; r < 4; ++r) {
      int jg = ks0 + m*16 + lq*4 + r;
      bool ok = (jg < ks1) && (jg >= ig - WIN) && (jg <= ig + WIN);
      float sv = ok ? sacc[m][r]*0.125f : -3.0e38f;
      sacc[m][r] = sv;
      mx = fmaxf(mx, sv);
    }
  mx = fmaxf(mx, __shfl_xor(mx, 16));
  mx = fmaxf(mx, __shfl_xor(mx, 32));
  float sum = 0.f;
  #pragma unroll
  for (int m = 0; m < 12; ++m)
    #pragma unroll
    for (int r = 0; r < 4; ++r) {
      float p = __expf(sacc[m][r] - mx);
      sacc[m][r] = p;
      sum += p;
    }
  sum += __shfl_xor(sum, 16);
  sum += __shfl_xor(sum, 32);
  const float inv = 1.0f / sum;

  u16* pw = &Pl[wave][0];
  #pragma unroll
  for (int m = 0; m < 12; ++m) {
    unsigned lo = (unsigned)f2b(sacc[m][0]*inv) | ((unsigned)f2b(sacc[m][1]*inv) << 16);
    unsigned hi = (unsigned)f2b(sacc[m][2]*inv) | ((unsigned)f2b(sacc[m][3]*inv) << 16);
    uint2 pk = make_uint2(lo, hi);
    *(uint2*)(&pw[l15*200 + m*16 + lq*4]) = pk;
  }

  f32x4 oacc[4] = {};
  #pragma unroll
  for (int kst = 0; kst < 6; ++kst) {
    bf16x8 pa = *(const bf16x8*)(&pw[l15*200 + kst*32 + lq*8]);
    #pragma unroll
    for (int n = 0; n < 4; ++n) {
      int d = n*16 + l15;
      int col = (((kst*4 + lq) ^ ((d >> 2) & 7)) << 3);
      bf16x8 vb = *(const bf16x8*)(&Vt[d*200 + col]);
      oacc[n] = __builtin_amdgcn_mfma_f32_16x16x32_bf16(pa, vb, oacc[n], 0, 0, 0);
    }
  }

  #pragma unroll
  for (int n = 0; n < 4; ++n)
    #pragma unroll
    for (int r = 0; r < 4; ++r) {
      int i = wave*16 + lq*4 + r;
      ctx[((size_t)b*SEQ + qs + i)*D_MODEL + h*DK + n*16 + l15] = f2b(oacc[n][r]);
    }
}

// ---------------- LayerNorm; optional bf16 mirror --------------------------
template<bool WB16>
__global__ __launch_bounds__(256)
void ln_kernel(const float* __restrict__ in, const float* __restrict__ g,
               const float* __restrict__ bb, float* __restrict__ out,
               u16* __restrict__ out16)
{
  const int row = blockIdx.x*4 + (threadIdx.x >> 6);
  const int lane = threadIdx.x & 63;
  const float* p = in + (size_t)row*D_MODEL + lane*8;
  float4 v0 = *(const float4*)(p);
  float4 v1 = *(const float4*)(p + 4);
  float s  = v0.x+v0.y+v0.z+v0.w + v1.x+v1.y+v1.z+v1.w;
  float sq = v0.x*v0.x+v0.y*v0.y+v0.z*v0.z+v0.w*v0.w
           + v1.x*v1.x+v1.y*v1.y+v1.z*v1.z+v1.w*v1.w;
  #pragma unroll
  for (int off = 32; off; off >>= 1) { s += __shfl_xor(s, off); sq += __shfl_xor(sq, off); }
  const float mean = s * (1.0f/D_MODEL);
  const float var  = sq * (1.0f/D_MODEL) - mean*mean;
  const float rstd = rsqrtf(var + 1e-5f);
  float4 g0 = *(const float4*)(g + lane*8);
  float4 g1 = *(const float4*)(g + lane*8 + 4);
  float4 b0 = *(const float4*)(bb + lane*8);
  float4 b1 = *(const float4*)(bb + lane*8 + 4);
  float4 o0, o1;
  o0.x = (v0.x-mean)*rstd*g0.x + b0.x;
  o0.y = (v0.y-mean)*rstd*g0.y + b0.y;
  o0.z = (v0.z-mean)*rstd*g0.z + b0.z;
  o0.w = (v0.w-mean)*rstd*g0.w + b0.w;
  o1.x = (v1.x-mean)*rstd*g1.x + b1.x;
  o1.y = (v1.y-mean)*rstd*g1.y + b1.y;
  o1.z = (v1.z-mean)*rstd*g1.z + b1.z;
  o1.w = (v1.w-mean)*rstd*g1.w + b1.w;
  float* qo = out + (size_t)row*D_MODEL + lane*8;
  *(float4*)(qo)     = o0;
  *(float4*)(qo + 4) = o1;
  if (WB16) {
    u16 hh[8];
    hh[0]=f2b(o0.x); hh[1]=f2b(o0.y); hh[2]=f2b(o0.z); hh[3]=f2b(o0.w);
    hh[4]=f2b(o1.x); hh[5]=f2b(o1.y); hh[6]=f2b(o1.z); hh[7]=f2b(o1.w);
    *(bf16x8*)(out16 + (size_t)row*D_MODEL + lane*8) = *(bf16x8*)&hh[0];
  }
}

extern "C" void kernel_launch(void* const* d_in, const int* in_sizes, int n_in,
                              void* d_out, int out_size, void* d_ws, size_t ws_size,
                              hipStream_t stream)
{
  (void)in_sizes; (void)n_in; (void)out_size; (void)ws_size;
  const float* x  = (const float*)d_in[0];
  const float* wq = (const float*)d_in[1];
  const float* bq = (const float*)d_in[2];
  const float* wk = (const float*)d_in[3];
  const float* bk = (const float*)d_in[4];
  const float* wv = (const float*)d_in[5];
  const float* bv = (const float*)d_in[6];
  const float* wo = (const float*)d_in[7];
  const float* bo = (const float*)d_in[8];
  const float* g1 = (const float*)d_in[9];
  const float* be1= (const float*)d_in[10];
  const float* w1 = (const float*)d_in[11];
  const float* b1 = (const float*)d_in[12];
  const float* w2 = (const float*)d_in[13];
  const float* b2 = (const float*)d_in[14];
  const float* g2 = (const float*)d_in[15];
  const float* be2= (const float*)d_in[16];

  const size_t RD = (size_t)ROWS * D_MODEL;   // 4.19M
  u16* W = (u16*)d_ws;
  u16*   xb   = W;
  u16*   qb   = W + RD;
  u16*   kb   = W + 2*RD;
  u16*   vb   = W + 3*RD;
  u16*   ctxb = W + 4*RD;
  u16*   hb16 = W + 5*RD;
  float* hbuf = (float*)(W + 6*RD);           // RD floats = 2RD u16
  u16*   wqt  = W + 8*RD;
  u16*   wkt  = wqt + 512*512;
  u16*   wvt  = wkt + 512*512;
  u16*   wot  = wvt + 512*512;
  u16*   w1t  = wot + 512*512;                // [2048][512]
  u16*   w2t  = w1t + 512*2048;               // [512][2048]
  u16*   ff1  = qb;                           // aliases qb..ctxb (4*RD = ROWS*2048)
  float* pre  = (float*)d_out;
  float* outp = (float*)d_out;

  dim3 blk(256);
  prep_kernel<<<dim3(1792), blk, 0, stream>>>(wq, wk, wv, wo, w1, w2, x,
                                              wqt, wkt, wvt, wot, w1t, w2t, xb);
  qkv_kernel<<<dim3(128,4,3), blk, 0, stream>>>(xb, wqt, bq, wkt, bk, wvt, bv, qb, kb, vb);
  attn_kernel<<<dim3(BATCH*NHEADS*32), blk, 0, stream>>>(qb, kb, vb, ctxb);
  gemm_bt<EP_RES><<<dim3(128,4), blk, 0, stream>>>(ctxb, wot, bo, x, pre, 512, 512);
  ln_kernel<true><<<dim3(ROWS/4), blk, 0, stream>>>(pre, g1, be1, hbuf, hb16);
  gemm_bt<EP_RELU><<<dim3(128,16), blk, 0, stream>>>(hb16, w1t, b1, nullptr, ff1, 512, 2048);
  gemm_bt<EP_RES><<<dim3(128,4), blk, 0, stream>>>(ff1, w2t, b2, hbuf, pre, 2048, 512);
  ln_kernel<false><<<dim3(ROWS/4), blk, 0, stream>>>(pre, g2, be2, outp, nullptr);
}